// Round 3
// baseline (960.629 us; speedup 1.0000x reference)
//
#include <hip/hip_runtime.h>

// Res_MCNN_branch2 on gfx950 — all convs f16 MFMA implicit-GEMM (16x16x32).
// R12: conv2/conv4 multi-tile pipelining with REGISTER staging (T14 split:
// global->reg loads for tile p+1 issued before tile p's K-loop, ds_write to
// the other LDS buffer after compute, one barrier per tile). R11's
// global_load_lds staging is REVERTED: rocprof showed 22x FETCH / 16x WRITE
// amplification (LDS-DMA does not coalesce lanes into shared 128B line
// fetches on 48B-record patterns) — empirically poisonous here.
// conv3 reverted to R10 single-buffer vector staging. conv1/conv5 = R10.
// Layouts: P1 NHWC24, P2 NHWC56, X3 NHWC24 (slim, R10). Frag K-spill into
// the next pixel record is safe (zero weights there; 16-half zeroed LDS tail
// per buffer keeps last-record reads finite).

typedef _Float16 half_t;
typedef _Float16 half8 __attribute__((ext_vector_type(8)));
typedef float floatx4 __attribute__((ext_vector_type(4)));

#define IN_H 768
#define IN_W 1024
#define P1H 384
#define P1W 512
#define P2H 192
#define P2W 256

// workspace offsets (bytes)
#define OFF_P2 0ULL                 // f16 [8][192][256][56] = 44,040,192
#define OFF_P1 44040192ULL          // f16 [8][384][512][24] = 75,497,472
#define OFF_X3 44040192ULL          // reuse P1 region after conv2
#define OFF_X4 0ULL                 // fp32 [8][192][256][10] reuse P2 region after conv3
#define OFF_W2 119537664ULL         // f16 [25][48][32] = 76,800 el
#define OFF_W3 119691264ULL         // f16 [25][32][64] = 102,400 el
#define OFF_W4 119896064ULL         // f16 [25][16][32] = 25,600 el
#define OFF_W1 119947264ULL         // f16 [7][32][32]  = 7,168 el

union PK4 { half_t h[4]; uint2 u; };
union U8 { half8 v; uint2 u[2]; };

// ---------------- weight pre-pack (fp32 OIHW -> f16 packed, linear) ----------------
__global__ __launch_bounds__(256) void pack_weights(
    const float* __restrict__ w2, const float* __restrict__ w3,
    const float* __restrict__ w4, const float* __restrict__ w1,
    half_t* __restrict__ wp2, half_t* __restrict__ wp3, half_t* __restrict__ wp4,
    half_t* __restrict__ wp1)
{
  int t = blockIdx.x * 256 + threadIdx.x;
  if (t < 38400) {                       // conv2: [25][48][32]
    int tap = t / 1536, r = t % 1536, oc = r >> 5, c = r & 31;
    float v = (oc < 40 && c < 20) ? w2[(oc * 20 + c) * 25 + tap] : 0.f;
    wp2[t] = (half_t)v;
  } else if (t < 89600) {                // conv3: [25][32][64]
    int u = t - 38400;
    int tap = u / 2048, r = u % 2048, oc = r >> 6, c = r & 63;
    float v = (oc < 20 && c < 40) ? w3[(oc * 40 + c) * 25 + tap] : 0.f;
    wp3[u] = (half_t)v;
  } else if (t < 102400) {               // conv4: [25][16][32]
    int u = t - 89600;
    int tap = u / 512, r = u % 512, oc = r >> 5, c = r & 31;
    float v = (oc < 10 && c < 20) ? w4[(oc * 20 + c) * 25 + tap] : 0.f;
    wp4[u] = (half_t)v;
  } else if (t < 109568) {               // conv1: [7][32][32], k = kx*4+c
    int u = t - 102400;
    int ky = u / 1024, r = u % 1024, oc = r >> 5, k = r & 31;
    int kx = k >> 2, c = k & 3;
    float v = (oc < 20 && c < 3 && kx < 7) ? w1[((oc * 3 + c) * 7 + ky) * 7 + kx] : 0.f;
    wp1[u] = (half_t)v;
  }
}

// ---------------- conv1 (3->20, 7x7, pad 3) MFMA + relu + pool -> P1 f16 NHWC24 ----------------
// 32-row tile, stage once (38x40 region, origin tx0-4 for float4 alignment),
// two K-loop passes p=0,1. Interior blocks: unguarded float4 staging.
__global__ __launch_bounds__(256) void conv1_mfma(
    const float* __restrict__ in, const half_t* __restrict__ wp,
    const float* __restrict__ bias, half_t* __restrict__ P1)
{
  __shared__ __align__(16) half_t ltile[38 * 40 * 4];   // 12160 B, row stride 40 px
  const int b = blockIdx.z, ty0 = blockIdx.y * 32, tx0 = blockIdx.x * 32;
  const int tid = threadIdx.x;
  const int HW1 = IN_H * IN_W;

  const float* p0 = in + (size_t)b * 3 * HW1;
  const bool interior = (blockIdx.x >= 1) && (blockIdx.x <= 30) &&
                        (blockIdx.y >= 1) && (blockIdx.y <= 22);
  if (interior) {
    for (int i = tid; i < 380; i += 256) {              // 38 rows x 10 float4
      int r = i / 10, c4 = i - r * 10;
      const float* pr = p0 + (size_t)(ty0 - 3 + r) * IN_W + (tx0 - 4 + 4 * c4);
      float4 v0 = *(const float4*)(pr);
      float4 v1 = *(const float4*)(pr + HW1);
      float4 v2 = *(const float4*)(pr + 2 * HW1);
      PK4 a0, a1, a2, a3;
      a0.h[0] = (half_t)v0.x; a0.h[1] = (half_t)v1.x; a0.h[2] = (half_t)v2.x; a0.h[3] = (half_t)0.f;
      a1.h[0] = (half_t)v0.y; a1.h[1] = (half_t)v1.y; a1.h[2] = (half_t)v2.y; a1.h[3] = (half_t)0.f;
      a2.h[0] = (half_t)v0.z; a2.h[1] = (half_t)v1.z; a2.h[2] = (half_t)v2.z; a2.h[3] = (half_t)0.f;
      a3.h[0] = (half_t)v0.w; a3.h[1] = (half_t)v1.w; a3.h[2] = (half_t)v2.w; a3.h[3] = (half_t)0.f;
      uint4* dst = (uint4*)(ltile + (r * 40 + 4 * c4) * 4);
      dst[0] = make_uint4(a0.u.x, a0.u.y, a1.u.x, a1.u.y);
      dst[1] = make_uint4(a2.u.x, a2.u.y, a3.u.x, a3.u.y);
    }
  } else {
    for (int i = tid; i < 1520; i += 256) {             // 38 rows x 40 cols, guarded
      int r = i / 40, c = i - r * 40;
      int gy = ty0 - 3 + r, gx = tx0 - 4 + c;
      float v0 = 0.f, v1 = 0.f, v2 = 0.f;
      if (gy >= 0 && gy < IN_H && (unsigned)gx < (unsigned)IN_W) {
        size_t o = (size_t)gy * IN_W + gx;
        v0 = p0[o];
        v1 = p0[o + HW1];
        v2 = p0[o + 2 * HW1];
      }
      PK4 pk;
      pk.h[0] = (half_t)v0; pk.h[1] = (half_t)v1;
      pk.h[2] = (half_t)v2; pk.h[3] = (half_t)0.f;
      *(uint2*)(ltile + (r * 40 + c) * 4) = pk.u;
    }
  }
  __syncthreads();

  const int wv = tid >> 6, ln = tid & 63, q = ln >> 4, nl = ln & 15;
  const int cbase = (2 * nl + 2 * q + 1) * 4;           // +1: tile origin tx0-4
  const half_t* wA = wp + nl * 32 + q * 8;

  floatx4 bv[2];
  #pragma unroll
  for (int mt = 0; mt < 2; ++mt)
    #pragma unroll
    for (int r = 0; r < 4; ++r) {
      int oc = mt * 16 + q * 4 + r;
      bv[mt][r] = (oc < 20) ? bias[oc] : 0.f;
    }
  const int pc = (tx0 >> 1) + nl;

  #pragma unroll
  for (int p = 0; p < 2; ++p) {
    const int rbase = p * 16 + 4 * wv;            // ltile row of this pass/wave
    U8 frag[4][2];
    #pragma unroll
    for (int d = 0; d < 4; ++d) {
      const half_t* rp = ltile + (rbase + d) * 160 + cbase;
      #pragma unroll
      for (int phx = 0; phx < 2; ++phx) {
        frag[d][phx].u[0] = *(const uint2*)(rp + phx * 4);
        frag[d][phx].u[1] = *(const uint2*)(rp + phx * 4 + 4);
      }
    }
    half8 Abuf[2][2];
    Abuf[0][0] = *(const half8*)(wA);
    Abuf[0][1] = *(const half8*)(wA + 512);
    floatx4 acc[2][8];
    #pragma unroll
    for (int mt = 0; mt < 2; ++mt)
      #pragma unroll
      for (int j = 0; j < 8; ++j) acc[mt][j] = (floatx4){0.f, 0.f, 0.f, 0.f};

    #pragma unroll
    for (int ky = 0; ky < 7; ++ky) {
      if (ky < 6) {
        Abuf[(ky + 1) & 1][0] = *(const half8*)(wA + (ky + 1) * 1024);
        Abuf[(ky + 1) & 1][1] = *(const half8*)(wA + (ky + 1) * 1024 + 512);
      }
      #pragma unroll
      for (int j = 0; j < 8; ++j) {
        const int g = j >> 2, ph = j & 3, phy = ph >> 1, phx = ph & 1;
        half8 B = frag[(2 * g + phy + ky) & 3][phx].v;
        acc[0][j] = __builtin_amdgcn_mfma_f32_16x16x32_f16(Abuf[ky & 1][0], B, acc[0][j], 0, 0, 0);
        acc[1][j] = __builtin_amdgcn_mfma_f32_16x16x32_f16(Abuf[ky & 1][1], B, acc[1][j], 0, 0, 0);
      }
      if (ky < 6) {                               // slide: ltile row rbase+ky+4 -> slot ky&3
        const half_t* rp = ltile + (rbase + ky + 4) * 160 + cbase;
        #pragma unroll
        for (int phx = 0; phx < 2; ++phx) {
          frag[ky & 3][phx].u[0] = *(const uint2*)(rp + phx * 4);
          frag[ky & 3][phx].u[1] = *(const uint2*)(rp + phx * 4 + 4);
        }
      }
    }

    const int pr0 = (ty0 >> 1) + 8 * p + 2 * wv;
    #pragma unroll
    for (int g = 0; g < 2; ++g) {
      size_t pxbase = (((size_t)b * P1H + pr0 + g) * P1W + pc) * 24;
      PK4 pk0;
      #pragma unroll
      for (int r = 0; r < 4; ++r) {
        float x = fmaxf(fmaxf(acc[0][g * 4 + 0][r], acc[0][g * 4 + 1][r]),
                        fmaxf(acc[0][g * 4 + 2][r], acc[0][g * 4 + 3][r]));
        pk0.h[r] = (half_t)fmaxf(x + bv[0][r], 0.f);
      }
      *(uint2*)(P1 + pxbase + q * 4) = pk0.u;           // oc 0..15
      if (q < 2) {                                      // oc 16..19 real, 20..23 = 0
        PK4 pk1;
        #pragma unroll
        for (int r = 0; r < 4; ++r) {
          float x = fmaxf(fmaxf(acc[1][g * 4 + 0][r], acc[1][g * 4 + 1][r]),
                          fmaxf(acc[1][g * 4 + 2][r], acc[1][g * 4 + 3][r]));
          pk1.h[r] = (half_t)fmaxf(x + bv[1][r], 0.f);
        }
        *(uint2*)(P1 + pxbase + 16 + q * 4) = pk1.u;
      }
    }
  }
}

// ---------------- conv2 (20->40, 5x5) MFMA + relu + pool -> P2 f16 NHWC56 ----------------
// 4 y-tiles per block, double-buffered LDS with register staging pipelined
// under the K-loop: loads for tile p+1 issued before tile p's compute,
// ds_write after, one barrier per tile.
__global__ __launch_bounds__(256, 2) void conv2_mfma(
    const half_t* __restrict__ P1, const half_t* __restrict__ wp,
    const float* __restrict__ bias, half_t* __restrict__ P2)
{
  #define C2_BUF 17296                               // 720*24 + 16-half zero tail
  __shared__ __align__(16) half_t lin[2 * C2_BUF];   // 69184 B
  const int b = blockIdx.z, ty_base = blockIdx.y * 64, tx0 = blockIdx.x * 32;
  const int tid = threadIdx.x;
  const int wv = tid >> 6, ln = tid & 63, q = ln >> 4, nl = ln & 15;

  if (tid < 16) {                                    // zero spill tails once
    lin[17280 + tid] = (half_t)0.f;
    lin[C2_BUF + 17280 + tid] = (half_t)0.f;
  }

  auto stage_load = [&](int sty0, uint4* stg) {      // global -> regs (9 x uint4)
    #pragma unroll
    for (int r = 0; r < 9; ++r) {
      int i = r * 256 + tid;
      uint4 v = make_uint4(0, 0, 0, 0);
      if (i < 2160) {
        int px = i / 3, part = i - px * 3;
        int row = px / 36, col = px - row * 36;
        int gy = sty0 - 2 + row, gx = tx0 - 2 + col;
        if ((unsigned)gy < (unsigned)P1H && (unsigned)gx < (unsigned)P1W)
          v = *(const uint4*)(P1 + (((size_t)b * P1H + gy) * P1W + gx) * 24 + part * 8);
      }
      stg[r] = v;
    }
  };
  auto stage_write = [&](int bufsel, const uint4* stg) {
    half_t* Lb = lin + bufsel * C2_BUF;
    #pragma unroll
    for (int r = 0; r < 9; ++r) {
      int i = r * 256 + tid;
      if (i < 2160) *(uint4*)(Lb + i * 8) = stg[r];
    }
  };

  const int cbase = 2 * nl * 24 + q * 8;             // + row*864 + c*24
  const half_t* wA = wp + nl * 32 + q * 8;
  floatx4 bv[3];
  #pragma unroll
  for (int mt = 0; mt < 3; ++mt)
    #pragma unroll
    for (int r = 0; r < 4; ++r) {
      int oc = mt * 16 + q * 4 + r;
      bv[mt][r] = (oc < 40) ? bias[oc] : 0.f;
    }
  const int pc = (tx0 >> 1) + nl;

  {                                                  // prologue: stage tile 0
    uint4 stg[9];
    stage_load(ty_base, stg);
    stage_write(0, stg);
  }
  __syncthreads();

  #pragma unroll 1
  for (int p = 0; p < 4; ++p) {
    uint4 stg[9];
    if (p < 3) stage_load(ty_base + (p + 1) * 16, stg);   // issue-early (T14)
    const half_t* L = lin + (p & 1) * C2_BUF;
    const int ty0 = ty_base + p * 16;

    half8 frag[4][6];
    #pragma unroll
    for (int d = 0; d < 4; ++d) {
      const half_t* rp = L + (4 * wv + d) * 864 + cbase;
      #pragma unroll
      for (int c = 0; c < 6; ++c) frag[d][c] = *(const half8*)(rp + c * 24);
    }
    half8 Abuf[2][3];
    #pragma unroll
    for (int mt = 0; mt < 3; ++mt) Abuf[0][mt] = *(const half8*)(wA + mt * 512);
    floatx4 acc[3][8];
    #pragma unroll
    for (int mt = 0; mt < 3; ++mt)
      #pragma unroll
      for (int j = 0; j < 8; ++j) acc[mt][j] = (floatx4){0.f, 0.f, 0.f, 0.f};

    #pragma unroll
    for (int ky = 0; ky < 5; ++ky) {
      #pragma unroll
      for (int kx = 0; kx < 5; ++kx) {
        const int tap = ky * 5 + kx;
        if (tap < 24) {
          #pragma unroll
          for (int mt = 0; mt < 3; ++mt)
            Abuf[(tap + 1) & 1][mt] = *(const half8*)(wA + (tap + 1) * 1536 + mt * 512);
        }
        #pragma unroll
        for (int j = 0; j < 8; ++j) {
          const int g = j >> 2, ph = j & 3, phy = ph >> 1, phx = ph & 1;
          half8 B = frag[(2 * g + phy + ky) & 3][kx + phx];
          acc[0][j] = __builtin_amdgcn_mfma_f32_16x16x32_f16(Abuf[tap & 1][0], B, acc[0][j], 0, 0, 0);
          acc[1][j] = __builtin_amdgcn_mfma_f32_16x16x32_f16(Abuf[tap & 1][1], B, acc[1][j], 0, 0, 0);
          acc[2][j] = __builtin_amdgcn_mfma_f32_16x16x32_f16(Abuf[tap & 1][2], B, acc[2][j], 0, 0, 0);
        }
      }
      if (ky < 4) {                                  // slide: row 4wv+ky+4 -> slot ky&3
        const half_t* rp = L + (4 * wv + ky + 4) * 864 + cbase;
        #pragma unroll
        for (int c = 0; c < 6; ++c) frag[ky & 3][c] = *(const half8*)(rp + c * 24);
      }
    }

    const int pr0 = (ty0 >> 1) + 2 * wv;
    #pragma unroll
    for (int g = 0; g < 2; ++g) {
      size_t pxbase = (((size_t)b * P2H + pr0 + g) * P2W + pc) * 56;
      #pragma unroll
      for (int mt = 0; mt < 3; ++mt) {
        PK4 pk;
        #pragma unroll
        for (int r = 0; r < 4; ++r) {
          float x = fmaxf(fmaxf(acc[mt][g * 4 + 0][r], acc[mt][g * 4 + 1][r]),
                          fmaxf(acc[mt][g * 4 + 2][r], acc[mt][g * 4 + 3][r]));
          pk.h[r] = (half_t)fmaxf(x + bv[mt][r], 0.f); // oc 40..47: 0+0 -> 0 pad
        }
        *(uint2*)(P2 + pxbase + mt * 16 + q * 4) = pk.u;
      }
      if (q == 0)
        *(uint4*)(P2 + pxbase + 48) = make_uint4(0, 0, 0, 0);  // halves 48..55 = 0
    }
    if (p < 3) {
      stage_write((p + 1) & 1, stg);                 // write-late into other buffer
      __syncthreads();                               // staged + buf[p] reads done
    }
  }
  #undef C2_BUF
}

// ---------------- conv3 (40->20, 5x5) MFMA + relu -> X3 f16 NHWC24 ----------------
// P2 records 56 halves (40 real + 16 zero). Single-buffer vector staging (R10).
__global__ __launch_bounds__(256, 2) void conv3_mfma(
    const half_t* __restrict__ P2, const half_t* __restrict__ wp,
    const float* __restrict__ bias, half_t* __restrict__ X3)
{
  __shared__ __align__(16) half_t lin[12 * 36 * 56 + 16];   // 48416 B
  const int b = blockIdx.z, ty0 = blockIdx.y * 8, tx0 = blockIdx.x * 32;
  const int tid = threadIdx.x;
  if (tid < 16) lin[12 * 36 * 56 + tid] = (half_t)0.f;
  for (int i = tid; i < 3024; i += 256) {              // 432 px x 7 uint4
    int px = i / 7, part = i - px * 7;
    int row = px / 36, col = px - row * 36;
    int gy = ty0 - 2 + row, gx = tx0 - 2 + col;
    uint4 v = make_uint4(0, 0, 0, 0);
    if (gy >= 0 && gy < P2H && (unsigned)gx < (unsigned)P2W)
      v = *(const uint4*)(P2 + (((size_t)b * P2H + gy) * P2W + gx) * 56 + part * 8);
    *(uint4*)(lin + px * 56 + part * 8) = v;
  }
  __syncthreads();

  const int wv = tid >> 6, ln = tid & 63, q = ln >> 4, nl = ln & 15;
  const int cbase = 2 * nl * 56 + q * 8;               // + row*2016 + c*56 + cb*32
  half8 frag[2][6][2];
  #pragma unroll
  for (int c = 0; c < 6; ++c)
    #pragma unroll
    for (int cb = 0; cb < 2; ++cb) {
      frag[0][c][cb] = *(const half8*)(lin + (2 * wv + 0) * 2016 + cbase + c * 56 + cb * 32);
      frag[1][c][cb] = *(const half8*)(lin + (2 * wv + 1) * 2016 + cbase + c * 56 + cb * 32);
    }
  const half_t* wA = wp + nl * 64 + q * 8;
  half8 Abuf[2][2][2];                                 // [parity][mt][cb]
  #pragma unroll
  for (int mt = 0; mt < 2; ++mt)
    #pragma unroll
    for (int cb = 0; cb < 2; ++cb)
      Abuf[0][mt][cb] = *(const half8*)(wA + mt * 1024 + cb * 32);
  floatx4 acc[2][4];
  #pragma unroll
  for (int mt = 0; mt < 2; ++mt)
    #pragma unroll
    for (int j = 0; j < 4; ++j) acc[mt][j] = (floatx4){0.f, 0.f, 0.f, 0.f};

  #pragma unroll
  for (int ky = 0; ky < 5; ++ky) {
    #pragma unroll
    for (int kx = 0; kx < 5; ++kx) {
      const int tap = ky * 5 + kx;
      if (tap < 24) {
        #pragma unroll
        for (int mt = 0; mt < 2; ++mt)
          #pragma unroll
          for (int cb = 0; cb < 2; ++cb)
            Abuf[(tap + 1) & 1][mt][cb] =
                *(const half8*)(wA + (tap + 1) * 2048 + mt * 1024 + cb * 32);
      }
      #pragma unroll
      for (int cb = 0; cb < 2; ++cb)
        #pragma unroll
        for (int j = 0; j < 4; ++j) {
          const int phy = j >> 1, phx = j & 1;
          half8 B = frag[(ky + phy) & 1][kx + phx][cb];
          acc[0][j] = __builtin_amdgcn_mfma_f32_16x16x32_f16(Abuf[tap & 1][0][cb], B, acc[0][j], 0, 0, 0);
          acc[1][j] = __builtin_amdgcn_mfma_f32_16x16x32_f16(Abuf[tap & 1][1][cb], B, acc[1][j], 0, 0, 0);
        }
    }
    if (ky < 4) {
      const half_t* rp = lin + (2 * wv + ky + 2) * 2016 + cbase;
      #pragma unroll
      for (int c = 0; c < 6; ++c)
        #pragma unroll
        for (int cb = 0; cb < 2; ++cb)
          frag[ky & 1][c][cb] = *(const half8*)(rp + c * 56 + cb * 32);
    }
  }

  floatx4 bv[2];
  #pragma unroll
  for (int mt = 0; mt < 2; ++mt)
    #pragma unroll
    for (int r = 0; r < 4; ++r) {
      int oc = mt * 16 + q * 4 + r;
      bv[mt][r] = (oc < 20) ? bias[oc] : 0.f;
    }
  #pragma unroll
  for (int j = 0; j < 4; ++j) {
    const int phy = j >> 1, phx = j & 1;
    int y = ty0 + 2 * wv + phy, x = tx0 + 2 * nl + phx;
    size_t pxbase = (((size_t)b * P2H + y) * P2W + x) * 24;
    #pragma unroll
    for (int mt = 0; mt < 2; ++mt) {
      if (mt == 1 && q >= 2) continue;                 // record is 24 halves
      floatx4 v = acc[mt][j];
      PK4 pk;
      #pragma unroll
      for (int r = 0; r < 4; ++r) pk.h[r] = (half_t)fmaxf(v[r] + bv[mt][r], 0.f);
      *(uint2*)(X3 + pxbase + mt * 16 + q * 4) = pk.u; // oc 20..23 auto-zero
    }
  }
}

// ---------------- conv4 (20->10, 5x5) MFMA + relu -> X4 fp32 NHWC10 ----------------
// 2 y-tiles per block, double-buffered LDS with register staging (as conv2).
__global__ __launch_bounds__(256, 2) void conv4_mfma(
    const half_t* __restrict__ X3, const half_t* __restrict__ wp,
    const float* __restrict__ bias, float* __restrict__ X4)
{
  #define C4_BUF 17296
  __shared__ __align__(16) half_t lin[2 * C4_BUF];     // 69184 B
  const int b = blockIdx.z, ty_base = blockIdx.y * 32, tx0 = blockIdx.x * 32;
  const int tid = threadIdx.x;
  const int wv = tid >> 6, ln = tid & 63, q = ln >> 4, nl = ln & 15;

  if (tid < 16) {
    lin[17280 + tid] = (half_t)0.f;
    lin[C4_BUF + 17280 + tid] = (half_t)0.f;
  }

  auto stage_load = [&](int sty0, uint4* stg) {
    #pragma unroll
    for (int r = 0; r < 9; ++r) {
      int i = r * 256 + tid;
      uint4 v = make_uint4(0, 0, 0, 0);
      if (i < 2160) {
        int px = i / 3, part = i - px * 3;
        int row = px / 36, col = px - row * 36;
        int gy = sty0 - 2 + row, gx = tx0 - 2 + col;
        if ((unsigned)gy < (unsigned)P2H && (unsigned)gx < (unsigned)P2W)
          v = *(const uint4*)(X3 + (((size_t)b * P2H + gy) * P2W + gx) * 24 + part * 8);
      }
      stg[r] = v;
    }
  };
  auto stage_write = [&](int bufsel, const uint4* stg) {
    half_t* Lb = lin + bufsel * C4_BUF;
    #pragma unroll
    for (int r = 0; r < 9; ++r) {
      int i = r * 256 + tid;
      if (i < 2160) *(uint4*)(Lb + i * 8) = stg[r];
    }
  };

  const int cbase = 2 * nl * 24 + q * 8;
  const half_t* wA = wp + nl * 32 + q * 8;
  float bv[4];
  #pragma unroll
  for (int r = 0; r < 4; ++r) {
    int oc = q * 4 + r;
    bv[r] = (oc < 10) ? bias[oc] : 0.f;
  }

  {
    uint4 stg[9];
    stage_load(ty_base, stg);
    stage_write(0, stg);
  }
  __syncthreads();

  #pragma unroll 1
  for (int p = 0; p < 2; ++p) {
    uint4 stg[9];
    if (p < 1) stage_load(ty_base + 16, stg);
    const half_t* L = lin + (p & 1) * C4_BUF;
    const int ty0 = ty_base + p * 16;

    half8 frag[4][6];
    #pragma unroll
    for (int d = 0; d < 4; ++d) {
      const half_t* rp = L + (4 * wv + d) * 864 + cbase;
      #pragma unroll
      for (int c = 0; c < 6; ++c) frag[d][c] = *(const half8*)(rp + c * 24);
    }
    half8 Abuf[2];
    Abuf[0] = *(const half8*)(wA);
    floatx4 acc[8];
    #pragma unroll
    for (int j = 0; j < 8; ++j) acc[j] = (floatx4){0.f, 0.f, 0.f, 0.f};

    #pragma unroll
    for (int ky = 0; ky < 5; ++ky) {
      #pragma unroll
      for (int kx = 0; kx < 5; ++kx) {
        const int tap = ky * 5 + kx;
        if (tap < 24) Abuf[(tap + 1) & 1] = *(const half8*)(wA + (tap + 1) * 512);
        #pragma unroll
        for (int j = 0; j < 8; ++j) {
          const int g = j >> 2, ph = j & 3, phy = ph >> 1, phx = ph & 1;
          half8 B = frag[(2 * g + phy + ky) & 3][kx + phx];
          acc[j] = __builtin_amdgcn_mfma_f32_16x16x32_f16(Abuf[tap & 1], B, acc[j], 0, 0, 0);
        }
      }
      if (ky < 4) {
        const half_t* rp = L + (4 * wv + ky + 4) * 864 + cbase;
        #pragma unroll
        for (int c = 0; c < 6; ++c) frag[ky & 3][c] = *(const half8*)(rp + c * 24);
      }
    }

    #pragma unroll
    for (int j = 0; j < 8; ++j) {
      const int g = j >> 2, ph = j & 3, phy = ph >> 1, phx = ph & 1;
      int y = ty0 + 4 * wv + 2 * g + phy, x = tx0 + 2 * nl + phx;
      float* dst = X4 + (((size_t)b * P2H + y) * P2W + x) * 10;
      floatx4 v = acc[j];
      float r0 = fmaxf(v[0] + bv[0], 0.f), r1 = fmaxf(v[1] + bv[1], 0.f);
      float r2 = fmaxf(v[2] + bv[2], 0.f), r3 = fmaxf(v[3] + bv[3], 0.f);
      if (q < 2) {
        *(float2*)(dst + q * 4)     = make_float2(r0, r1);
        *(float2*)(dst + q * 4 + 2) = make_float2(r2, r3);
      } else if (q == 2) {
        *(float2*)(dst + 8) = make_float2(r0, r1);   // oc 8,9
      }
    }
    if (p < 1) {
      stage_write(1, stg);
      __syncthreads();
    }
  }
  #undef C4_BUF
}

// ---------------- conv5 (10->1, 1x1) + gray residual + relu ----------------
// Gray loads as float4 at col 4j (lane j): 64 lanes = contiguous 1KB, coalesced.
__global__ __launch_bounds__(256) void conv5_res(
    const float* __restrict__ X4, const float* __restrict__ w5,
    const float* __restrict__ b5, const float* __restrict__ in,
    float* __restrict__ out)
{
  const int idx = blockIdx.x * 256 + threadIdx.x;  // 0 .. 8*192*256-1
  const int j = idx & 255;
  const int bi = idx >> 8;
  const int i = bi % 192;
  const int b = bi / 192;
  const float* xp = X4 + (((size_t)b * P2H + i) * P2W + j) * 10;
  float sum = b5[0];
  #pragma unroll
  for (int c = 0; c < 10; ++c) sum += w5[c] * xp[c];
  const int r0 = 4 * i + 1;
  const size_t cb = (size_t)r0 * IN_W + 4 * j;     // float4 covers cols 4j..4j+3
  float g = 0.f;
  #pragma unroll
  for (int ch = 0; ch < 3; ++ch) {
    const float coef = (ch == 0) ? 0.299f : ((ch == 1) ? 0.587f : 0.114f);
    const float* q = in + ((size_t)b * 3 + ch) * IN_H * IN_W;
    float4 a = *(const float4*)(q + cb);
    float4 d = *(const float4*)(q + cb + IN_W);
    g += coef * (a.y + a.z + d.y + d.z);           // cols 4j+1, 4j+2
  }
  g *= 0.25f;
  out[idx] = fmaxf(sum + fmaxf(g, 0.f), 0.f);
}

extern "C" void kernel_launch(void* const* d_in, const int* in_sizes, int n_in,
                              void* d_out, int out_size, void* d_ws, size_t ws_size,
                              hipStream_t stream) {
  const float* input = (const float*)d_in[0];
  const float* w1 = (const float*)d_in[1];  const float* b1 = (const float*)d_in[2];
  const float* w2 = (const float*)d_in[3];  const float* b2 = (const float*)d_in[4];
  const float* w3 = (const float*)d_in[5];  const float* b3 = (const float*)d_in[6];
  const float* w4 = (const float*)d_in[7];  const float* b4 = (const float*)d_in[8];
  const float* w5 = (const float*)d_in[9];  const float* b5 = (const float*)d_in[10];
  float* out = (float*)d_out;
  char* ws = (char*)d_ws;

  half_t* P2h = (half_t*)(ws + OFF_P2);
  half_t* P1h = (half_t*)(ws + OFF_P1);
  half_t* X3h = (half_t*)(ws + OFF_X3);
  float*  X4f = (float*)(ws + OFF_X4);
  half_t* wp2 = (half_t*)(ws + OFF_W2);
  half_t* wp3 = (half_t*)(ws + OFF_W3);
  half_t* wp4 = (half_t*)(ws + OFF_W4);
  half_t* wp1 = (half_t*)(ws + OFF_W1);

  pack_weights<<<432, 256, 0, stream>>>(w2, w3, w4, w1, wp2, wp3, wp4, wp1);
  conv1_mfma<<<dim3(32, 24, 8), 256, 0, stream>>>(input, wp1, b1, P1h);
  conv2_mfma<<<dim3(16, 6, 8), 256, 0, stream>>>(P1h, wp2, b2, P2h);
  conv3_mfma<<<dim3(8, 24, 8), 256, 0, stream>>>(P2h, wp3, b3, X3h);
  conv4_mfma<<<dim3(8, 6, 8), 256, 0, stream>>>(X3h, wp4, b4, X4f);
  conv5_res<<<1536, 256, 0, stream>>>(X4f, w5, b5, input, out);
}

// Round 4
// 379.313 us; speedup vs baseline: 2.5326x; 2.5326x over previous
//
#include <hip/hip_runtime.h>

// Res_MCNN_branch2 on gfx950 — all convs f16 MFMA implicit-GEMM (16x16x32).
// R13 = R10 (proven 385 µs) + conv5 fused into conv4's epilogue.
// R11/R12 multi-tile pipelining REVERTED: both showed ~985 MB FETCH / ~777 MB
// WRITE (vs R10's 43/43) regardless of staging method — the 4-tile loop's
// extra live state (VGPR 108->128 cap) spilled to scratch; scratch traffic
// dominates FETCH/WRITE. Do not re-add staging state to conv2's K-loop.
// conv4+conv5 fusion: lanes q=0..3 hold the same output pixel (different oc),
// so conv5's 1x1 dot = per-lane partial + shfl_xor(16)+shfl_xor(32); q==0
// lanes add the gray bilinear residual (float4-pair loads, 512B/wave
// contiguous) and write out as float2. X4 tensor eliminated entirely.
// Layouts: P1 NHWC24, P2 NHWC56, X3 NHWC24 (slim, R10). Frag K-spill into
// the next pixel record is safe (zero weights there; 16-half zeroed LDS tail).

typedef _Float16 half_t;
typedef _Float16 half8 __attribute__((ext_vector_type(8)));
typedef float floatx4 __attribute__((ext_vector_type(4)));

#define IN_H 768
#define IN_W 1024
#define P1H 384
#define P1W 512
#define P2H 192
#define P2W 256

// workspace offsets (bytes)
#define OFF_P2 0ULL                 // f16 [8][192][256][56] = 44,040,192
#define OFF_P1 44040192ULL          // f16 [8][384][512][24] = 75,497,472
#define OFF_X3 44040192ULL          // reuse P1 region after conv2
#define OFF_W2 119537664ULL         // f16 [25][48][32] = 76,800 el
#define OFF_W3 119691264ULL         // f16 [25][32][64] = 102,400 el
#define OFF_W4 119896064ULL         // f16 [25][16][32] = 25,600 el
#define OFF_W1 119947264ULL         // f16 [7][32][32]  = 7,168 el

union PK4 { half_t h[4]; uint2 u; };
union U8 { half8 v; uint2 u[2]; };

// ---------------- weight pre-pack (fp32 OIHW -> f16 packed, linear) ----------------
__global__ __launch_bounds__(256) void pack_weights(
    const float* __restrict__ w2, const float* __restrict__ w3,
    const float* __restrict__ w4, const float* __restrict__ w1,
    half_t* __restrict__ wp2, half_t* __restrict__ wp3, half_t* __restrict__ wp4,
    half_t* __restrict__ wp1)
{
  int t = blockIdx.x * 256 + threadIdx.x;
  if (t < 38400) {                       // conv2: [25][48][32]
    int tap = t / 1536, r = t % 1536, oc = r >> 5, c = r & 31;
    float v = (oc < 40 && c < 20) ? w2[(oc * 20 + c) * 25 + tap] : 0.f;
    wp2[t] = (half_t)v;
  } else if (t < 89600) {                // conv3: [25][32][64]
    int u = t - 38400;
    int tap = u / 2048, r = u % 2048, oc = r >> 6, c = r & 63;
    float v = (oc < 20 && c < 40) ? w3[(oc * 40 + c) * 25 + tap] : 0.f;
    wp3[u] = (half_t)v;
  } else if (t < 102400) {               // conv4: [25][16][32]
    int u = t - 89600;
    int tap = u / 512, r = u % 512, oc = r >> 5, c = r & 31;
    float v = (oc < 10 && c < 20) ? w4[(oc * 20 + c) * 25 + tap] : 0.f;
    wp4[u] = (half_t)v;
  } else if (t < 109568) {               // conv1: [7][32][32], k = kx*4+c
    int u = t - 102400;
    int ky = u / 1024, r = u % 1024, oc = r >> 5, k = r & 31;
    int kx = k >> 2, c = k & 3;
    float v = (oc < 20 && c < 3 && kx < 7) ? w1[((oc * 3 + c) * 7 + ky) * 7 + kx] : 0.f;
    wp1[u] = (half_t)v;
  }
}

// ---------------- conv1 (3->20, 7x7, pad 3) MFMA + relu + pool -> P1 f16 NHWC24 ----------------
// 32-row tile, stage once (38x40 region, origin tx0-4 for float4 alignment),
// two K-loop passes p=0,1. Interior blocks: unguarded float4 staging.
__global__ __launch_bounds__(256) void conv1_mfma(
    const float* __restrict__ in, const half_t* __restrict__ wp,
    const float* __restrict__ bias, half_t* __restrict__ P1)
{
  __shared__ __align__(16) half_t ltile[38 * 40 * 4];   // 12160 B, row stride 40 px
  const int b = blockIdx.z, ty0 = blockIdx.y * 32, tx0 = blockIdx.x * 32;
  const int tid = threadIdx.x;
  const int HW1 = IN_H * IN_W;

  const float* p0 = in + (size_t)b * 3 * HW1;
  const bool interior = (blockIdx.x >= 1) && (blockIdx.x <= 30) &&
                        (blockIdx.y >= 1) && (blockIdx.y <= 22);
  if (interior) {
    for (int i = tid; i < 380; i += 256) {              // 38 rows x 10 float4
      int r = i / 10, c4 = i - r * 10;
      const float* pr = p0 + (size_t)(ty0 - 3 + r) * IN_W + (tx0 - 4 + 4 * c4);
      float4 v0 = *(const float4*)(pr);
      float4 v1 = *(const float4*)(pr + HW1);
      float4 v2 = *(const float4*)(pr + 2 * HW1);
      PK4 a0, a1, a2, a3;
      a0.h[0] = (half_t)v0.x; a0.h[1] = (half_t)v1.x; a0.h[2] = (half_t)v2.x; a0.h[3] = (half_t)0.f;
      a1.h[0] = (half_t)v0.y; a1.h[1] = (half_t)v1.y; a1.h[2] = (half_t)v2.y; a1.h[3] = (half_t)0.f;
      a2.h[0] = (half_t)v0.z; a2.h[1] = (half_t)v1.z; a2.h[2] = (half_t)v2.z; a2.h[3] = (half_t)0.f;
      a3.h[0] = (half_t)v0.w; a3.h[1] = (half_t)v1.w; a3.h[2] = (half_t)v2.w; a3.h[3] = (half_t)0.f;
      uint4* dst = (uint4*)(ltile + (r * 40 + 4 * c4) * 4);
      dst[0] = make_uint4(a0.u.x, a0.u.y, a1.u.x, a1.u.y);
      dst[1] = make_uint4(a2.u.x, a2.u.y, a3.u.x, a3.u.y);
    }
  } else {
    for (int i = tid; i < 1520; i += 256) {             // 38 rows x 40 cols, guarded
      int r = i / 40, c = i - r * 40;
      int gy = ty0 - 3 + r, gx = tx0 - 4 + c;
      float v0 = 0.f, v1 = 0.f, v2 = 0.f;
      if (gy >= 0 && gy < IN_H && (unsigned)gx < (unsigned)IN_W) {
        size_t o = (size_t)gy * IN_W + gx;
        v0 = p0[o];
        v1 = p0[o + HW1];
        v2 = p0[o + 2 * HW1];
      }
      PK4 pk;
      pk.h[0] = (half_t)v0; pk.h[1] = (half_t)v1;
      pk.h[2] = (half_t)v2; pk.h[3] = (half_t)0.f;
      *(uint2*)(ltile + (r * 40 + c) * 4) = pk.u;
    }
  }
  __syncthreads();

  const int wv = tid >> 6, ln = tid & 63, q = ln >> 4, nl = ln & 15;
  const int cbase = (2 * nl + 2 * q + 1) * 4;           // +1: tile origin tx0-4
  const half_t* wA = wp + nl * 32 + q * 8;

  floatx4 bv[2];
  #pragma unroll
  for (int mt = 0; mt < 2; ++mt)
    #pragma unroll
    for (int r = 0; r < 4; ++r) {
      int oc = mt * 16 + q * 4 + r;
      bv[mt][r] = (oc < 20) ? bias[oc] : 0.f;
    }
  const int pc = (tx0 >> 1) + nl;

  #pragma unroll
  for (int p = 0; p < 2; ++p) {
    const int rbase = p * 16 + 4 * wv;            // ltile row of this pass/wave
    U8 frag[4][2];
    #pragma unroll
    for (int d = 0; d < 4; ++d) {
      const half_t* rp = ltile + (rbase + d) * 160 + cbase;
      #pragma unroll
      for (int phx = 0; phx < 2; ++phx) {
        frag[d][phx].u[0] = *(const uint2*)(rp + phx * 4);
        frag[d][phx].u[1] = *(const uint2*)(rp + phx * 4 + 4);
      }
    }
    half8 Abuf[2][2];
    Abuf[0][0] = *(const half8*)(wA);
    Abuf[0][1] = *(const half8*)(wA + 512);
    floatx4 acc[2][8];
    #pragma unroll
    for (int mt = 0; mt < 2; ++mt)
      #pragma unroll
      for (int j = 0; j < 8; ++j) acc[mt][j] = (floatx4){0.f, 0.f, 0.f, 0.f};

    #pragma unroll
    for (int ky = 0; ky < 7; ++ky) {
      if (ky < 6) {
        Abuf[(ky + 1) & 1][0] = *(const half8*)(wA + (ky + 1) * 1024);
        Abuf[(ky + 1) & 1][1] = *(const half8*)(wA + (ky + 1) * 1024 + 512);
      }
      #pragma unroll
      for (int j = 0; j < 8; ++j) {
        const int g = j >> 2, ph = j & 3, phy = ph >> 1, phx = ph & 1;
        half8 B = frag[(2 * g + phy + ky) & 3][phx].v;
        acc[0][j] = __builtin_amdgcn_mfma_f32_16x16x32_f16(Abuf[ky & 1][0], B, acc[0][j], 0, 0, 0);
        acc[1][j] = __builtin_amdgcn_mfma_f32_16x16x32_f16(Abuf[ky & 1][1], B, acc[1][j], 0, 0, 0);
      }
      if (ky < 6) {                               // slide: ltile row rbase+ky+4 -> slot ky&3
        const half_t* rp = ltile + (rbase + ky + 4) * 160 + cbase;
        #pragma unroll
        for (int phx = 0; phx < 2; ++phx) {
          frag[ky & 3][phx].u[0] = *(const uint2*)(rp + phx * 4);
          frag[ky & 3][phx].u[1] = *(const uint2*)(rp + phx * 4 + 4);
        }
      }
    }

    const int pr0 = (ty0 >> 1) + 8 * p + 2 * wv;
    #pragma unroll
    for (int g = 0; g < 2; ++g) {
      size_t pxbase = (((size_t)b * P1H + pr0 + g) * P1W + pc) * 24;
      PK4 pk0;
      #pragma unroll
      for (int r = 0; r < 4; ++r) {
        float x = fmaxf(fmaxf(acc[0][g * 4 + 0][r], acc[0][g * 4 + 1][r]),
                        fmaxf(acc[0][g * 4 + 2][r], acc[0][g * 4 + 3][r]));
        pk0.h[r] = (half_t)fmaxf(x + bv[0][r], 0.f);
      }
      *(uint2*)(P1 + pxbase + q * 4) = pk0.u;           // oc 0..15
      if (q < 2) {                                      // oc 16..19 real, 20..23 = 0
        PK4 pk1;
        #pragma unroll
        for (int r = 0; r < 4; ++r) {
          float x = fmaxf(fmaxf(acc[1][g * 4 + 0][r], acc[1][g * 4 + 1][r]),
                          fmaxf(acc[1][g * 4 + 2][r], acc[1][g * 4 + 3][r]));
          pk1.h[r] = (half_t)fmaxf(x + bv[1][r], 0.f);
        }
        *(uint2*)(P1 + pxbase + 16 + q * 4) = pk1.u;
      }
    }
  }
}

// ---------------- conv2 (20->40, 5x5) MFMA + relu + pool -> P2 f16 NHWC56 ----------------
// N=128/wave: 16x32 conv tile. P1 records 24 halves; frag q>=2 spills into the
// next record (zero weights there). Window frag[4][6]; A depth-1 prefetch.
__global__ __launch_bounds__(256, 2) void conv2_mfma(
    const half_t* __restrict__ P1, const half_t* __restrict__ wp,
    const float* __restrict__ bias, half_t* __restrict__ P2)
{
  __shared__ __align__(16) half_t lin[20 * 36 * 24 + 16];   // 34592 B (16-half zero tail)
  const int b = blockIdx.z, ty0 = blockIdx.y * 16, tx0 = blockIdx.x * 32;
  const int tid = threadIdx.x;
  if (tid < 16) lin[20 * 36 * 24 + tid] = (half_t)0.f;
  for (int i = tid; i < 2160; i += 256) {              // 720 px x 3 uint4
    int px = i / 3, part = i - px * 3;
    int row = px / 36, col = px - row * 36;
    int gy = ty0 - 2 + row, gx = tx0 - 2 + col;
    uint4 v = make_uint4(0, 0, 0, 0);
    if (gy >= 0 && gy < P1H && (unsigned)gx < (unsigned)P1W)
      v = *(const uint4*)(P1 + (((size_t)b * P1H + gy) * P1W + gx) * 24 + part * 8);
    *(uint4*)(lin + px * 24 + part * 8) = v;
  }
  __syncthreads();

  const int wv = tid >> 6, ln = tid & 63, q = ln >> 4, nl = ln & 15;
  const int cbase = 2 * nl * 24 + q * 8;               // + row*864 + c*24
  half8 frag[4][6];
  #pragma unroll
  for (int d = 0; d < 4; ++d) {
    const half_t* rp = lin + (4 * wv + d) * 864 + cbase;
    #pragma unroll
    for (int c = 0; c < 6; ++c) frag[d][c] = *(const half8*)(rp + c * 24);
  }
  const half_t* wA = wp + nl * 32 + q * 8;
  half8 Abuf[2][3];
  #pragma unroll
  for (int mt = 0; mt < 3; ++mt) Abuf[0][mt] = *(const half8*)(wA + mt * 512);
  floatx4 acc[3][8];
  #pragma unroll
  for (int mt = 0; mt < 3; ++mt)
    #pragma unroll
    for (int j = 0; j < 8; ++j) acc[mt][j] = (floatx4){0.f, 0.f, 0.f, 0.f};

  #pragma unroll
  for (int ky = 0; ky < 5; ++ky) {
    #pragma unroll
    for (int kx = 0; kx < 5; ++kx) {
      const int tap = ky * 5 + kx;
      if (tap < 24) {
        #pragma unroll
        for (int mt = 0; mt < 3; ++mt)
          Abuf[(tap + 1) & 1][mt] = *(const half8*)(wA + (tap + 1) * 1536 + mt * 512);
      }
      #pragma unroll
      for (int j = 0; j < 8; ++j) {
        const int g = j >> 2, ph = j & 3, phy = ph >> 1, phx = ph & 1;
        half8 B = frag[(2 * g + phy + ky) & 3][kx + phx];
        acc[0][j] = __builtin_amdgcn_mfma_f32_16x16x32_f16(Abuf[tap & 1][0], B, acc[0][j], 0, 0, 0);
        acc[1][j] = __builtin_amdgcn_mfma_f32_16x16x32_f16(Abuf[tap & 1][1], B, acc[1][j], 0, 0, 0);
        acc[2][j] = __builtin_amdgcn_mfma_f32_16x16x32_f16(Abuf[tap & 1][2], B, acc[2][j], 0, 0, 0);
      }
    }
    if (ky < 4) {                                      // slide: row 4wv+ky+4 -> slot ky&3
      const half_t* rp = lin + (4 * wv + ky + 4) * 864 + cbase;
      #pragma unroll
      for (int c = 0; c < 6; ++c) frag[ky & 3][c] = *(const half8*)(rp + c * 24);
    }
  }

  floatx4 bv[3];
  #pragma unroll
  for (int mt = 0; mt < 3; ++mt)
    #pragma unroll
    for (int r = 0; r < 4; ++r) {
      int oc = mt * 16 + q * 4 + r;
      bv[mt][r] = (oc < 40) ? bias[oc] : 0.f;
    }
  const int pr0 = (ty0 >> 1) + 2 * wv;
  const int pc = (tx0 >> 1) + nl;
  #pragma unroll
  for (int g = 0; g < 2; ++g) {
    size_t pxbase = (((size_t)b * P2H + pr0 + g) * P2W + pc) * 56;
    #pragma unroll
    for (int mt = 0; mt < 3; ++mt) {
      PK4 pk;
      #pragma unroll
      for (int r = 0; r < 4; ++r) {
        float x = fmaxf(fmaxf(acc[mt][g * 4 + 0][r], acc[mt][g * 4 + 1][r]),
                        fmaxf(acc[mt][g * 4 + 2][r], acc[mt][g * 4 + 3][r]));
        pk.h[r] = (half_t)fmaxf(x + bv[mt][r], 0.f);   // oc 40..47: 0+0 -> 0 pad
      }
      *(uint2*)(P2 + pxbase + mt * 16 + q * 4) = pk.u;
    }
    if (q == 0)
      *(uint4*)(P2 + pxbase + 48) = make_uint4(0, 0, 0, 0);  // halves 48..55 = 0
  }
}

// ---------------- conv3 (40->20, 5x5) MFMA + relu -> X3 f16 NHWC24 ----------------
// P2 records 56 halves (40 real + 16 zero). Window frag[2][6][2cb] + A prefetch.
__global__ __launch_bounds__(256, 2) void conv3_mfma(
    const half_t* __restrict__ P2, const half_t* __restrict__ wp,
    const float* __restrict__ bias, half_t* __restrict__ X3)
{
  __shared__ __align__(16) half_t lin[12 * 36 * 56 + 16];   // 48416 B
  const int b = blockIdx.z, ty0 = blockIdx.y * 8, tx0 = blockIdx.x * 32;
  const int tid = threadIdx.x;
  if (tid < 16) lin[12 * 36 * 56 + tid] = (half_t)0.f;
  for (int i = tid; i < 3024; i += 256) {              // 432 px x 7 uint4
    int px = i / 7, part = i - px * 7;
    int row = px / 36, col = px - row * 36;
    int gy = ty0 - 2 + row, gx = tx0 - 2 + col;
    uint4 v = make_uint4(0, 0, 0, 0);
    if (gy >= 0 && gy < P2H && (unsigned)gx < (unsigned)P2W)
      v = *(const uint4*)(P2 + (((size_t)b * P2H + gy) * P2W + gx) * 56 + part * 8);
    *(uint4*)(lin + px * 56 + part * 8) = v;
  }
  __syncthreads();

  const int wv = tid >> 6, ln = tid & 63, q = ln >> 4, nl = ln & 15;
  const int cbase = 2 * nl * 56 + q * 8;               // + row*2016 + c*56 + cb*32
  half8 frag[2][6][2];
  #pragma unroll
  for (int c = 0; c < 6; ++c)
    #pragma unroll
    for (int cb = 0; cb < 2; ++cb) {
      frag[0][c][cb] = *(const half8*)(lin + (2 * wv + 0) * 2016 + cbase + c * 56 + cb * 32);
      frag[1][c][cb] = *(const half8*)(lin + (2 * wv + 1) * 2016 + cbase + c * 56 + cb * 32);
    }
  const half_t* wA = wp + nl * 64 + q * 8;
  half8 Abuf[2][2][2];                                 // [parity][mt][cb]
  #pragma unroll
  for (int mt = 0; mt < 2; ++mt)
    #pragma unroll
    for (int cb = 0; cb < 2; ++cb)
      Abuf[0][mt][cb] = *(const half8*)(wA + mt * 1024 + cb * 32);
  floatx4 acc[2][4];
  #pragma unroll
  for (int mt = 0; mt < 2; ++mt)
    #pragma unroll
    for (int j = 0; j < 4; ++j) acc[mt][j] = (floatx4){0.f, 0.f, 0.f, 0.f};

  #pragma unroll
  for (int ky = 0; ky < 5; ++ky) {
    #pragma unroll
    for (int kx = 0; kx < 5; ++kx) {
      const int tap = ky * 5 + kx;
      if (tap < 24) {
        #pragma unroll
        for (int mt = 0; mt < 2; ++mt)
          #pragma unroll
          for (int cb = 0; cb < 2; ++cb)
            Abuf[(tap + 1) & 1][mt][cb] =
                *(const half8*)(wA + (tap + 1) * 2048 + mt * 1024 + cb * 32);
      }
      #pragma unroll
      for (int cb = 0; cb < 2; ++cb)
        #pragma unroll
        for (int j = 0; j < 4; ++j) {
          const int phy = j >> 1, phx = j & 1;
          half8 B = frag[(ky + phy) & 1][kx + phx][cb];
          acc[0][j] = __builtin_amdgcn_mfma_f32_16x16x32_f16(Abuf[tap & 1][0][cb], B, acc[0][j], 0, 0, 0);
          acc[1][j] = __builtin_amdgcn_mfma_f32_16x16x32_f16(Abuf[tap & 1][1][cb], B, acc[1][j], 0, 0, 0);
        }
    }
    if (ky < 4) {
      const half_t* rp = lin + (2 * wv + ky + 2) * 2016 + cbase;
      #pragma unroll
      for (int c = 0; c < 6; ++c)
        #pragma unroll
        for (int cb = 0; cb < 2; ++cb)
          frag[ky & 1][c][cb] = *(const half8*)(rp + c * 56 + cb * 32);
    }
  }

  floatx4 bv[2];
  #pragma unroll
  for (int mt = 0; mt < 2; ++mt)
    #pragma unroll
    for (int r = 0; r < 4; ++r) {
      int oc = mt * 16 + q * 4 + r;
      bv[mt][r] = (oc < 20) ? bias[oc] : 0.f;
    }
  #pragma unroll
  for (int j = 0; j < 4; ++j) {
    const int phy = j >> 1, phx = j & 1;
    int y = ty0 + 2 * wv + phy, x = tx0 + 2 * nl + phx;
    size_t pxbase = (((size_t)b * P2H + y) * P2W + x) * 24;
    #pragma unroll
    for (int mt = 0; mt < 2; ++mt) {
      if (mt == 1 && q >= 2) continue;                 // record is 24 halves
      floatx4 v = acc[mt][j];
      PK4 pk;
      #pragma unroll
      for (int r = 0; r < 4; ++r) pk.h[r] = (half_t)fmaxf(v[r] + bv[mt][r], 0.f);
      *(uint2*)(X3 + pxbase + mt * 16 + q * 4) = pk.u; // oc 20..23 auto-zero
    }
  }
}

// ---------------- conv4 (20->10, 5x5) + conv5 (10->1, 1x1) + gray residual + relu ----------------
// X3 records 24 halves. N=128/wave: 16x32 tile, window frag[4][6], A prefetch.
// Fused epilogue: lanes q=0..3 hold the same pixel (different oc) -> per-lane
// w5 partial, shfl_xor(16)+shfl_xor(32) reduce, q==0 adds gray + writes out.
__global__ __launch_bounds__(256, 2) void conv4_mfma(
    const half_t* __restrict__ X3, const half_t* __restrict__ wp,
    const float* __restrict__ bias, const float* __restrict__ w5,
    const float* __restrict__ b5, const float* __restrict__ in,
    float* __restrict__ out)
{
  __shared__ __align__(16) half_t lin[20 * 36 * 24 + 16];   // 34592 B
  const int b = blockIdx.z, ty0 = blockIdx.y * 16, tx0 = blockIdx.x * 32;
  const int tid = threadIdx.x;
  if (tid < 16) lin[20 * 36 * 24 + tid] = (half_t)0.f;
  for (int i = tid; i < 2160; i += 256) {
    int px = i / 3, part = i - px * 3;
    int row = px / 36, col = px - row * 36;
    int gy = ty0 - 2 + row, gx = tx0 - 2 + col;
    uint4 v = make_uint4(0, 0, 0, 0);
    if (gy >= 0 && gy < P2H && (unsigned)gx < (unsigned)P2W)
      v = *(const uint4*)(X3 + (((size_t)b * P2H + gy) * P2W + gx) * 24 + part * 8);
    *(uint4*)(lin + px * 24 + part * 8) = v;
  }
  __syncthreads();

  const int wv = tid >> 6, ln = tid & 63, q = ln >> 4, nl = ln & 15;
  const int cbase = 2 * nl * 24 + q * 8;
  half8 frag[4][6];
  #pragma unroll
  for (int d = 0; d < 4; ++d) {
    const half_t* rp = lin + (4 * wv + d) * 864 + cbase;
    #pragma unroll
    for (int c = 0; c < 6; ++c) frag[d][c] = *(const half8*)(rp + c * 24);
  }
  const half_t* wA = wp + nl * 32 + q * 8;
  half8 Abuf[2];
  Abuf[0] = *(const half8*)(wA);
  floatx4 acc[8];
  #pragma unroll
  for (int j = 0; j < 8; ++j) acc[j] = (floatx4){0.f, 0.f, 0.f, 0.f};

  #pragma unroll
  for (int ky = 0; ky < 5; ++ky) {
    #pragma unroll
    for (int kx = 0; kx < 5; ++kx) {
      const int tap = ky * 5 + kx;
      if (tap < 24) Abuf[(tap + 1) & 1] = *(const half8*)(wA + (tap + 1) * 512);
      #pragma unroll
      for (int j = 0; j < 8; ++j) {
        const int g = j >> 2, ph = j & 3, phy = ph >> 1, phx = ph & 1;
        half8 B = frag[(2 * g + phy + ky) & 3][kx + phx];
        acc[j] = __builtin_amdgcn_mfma_f32_16x16x32_f16(Abuf[tap & 1], B, acc[j], 0, 0, 0);
      }
    }
    if (ky < 4) {
      const half_t* rp = lin + (4 * wv + ky + 4) * 864 + cbase;
      #pragma unroll
      for (int c = 0; c < 6; ++c) frag[ky & 3][c] = *(const half8*)(rp + c * 24);
    }
  }

  float bv[4], w5v[4];
  #pragma unroll
  for (int r = 0; r < 4; ++r) {
    int oc = q * 4 + r;
    bv[r]  = (oc < 10) ? bias[oc] : 0.f;
    w5v[r] = (oc < 10) ? w5[oc] : 0.f;
  }
  const float b5v = b5[0];
  const float* inb = in + (size_t)b * 3 * (IN_H * IN_W);

  #pragma unroll
  for (int g = 0; g < 2; ++g)
    #pragma unroll
    for (int phy = 0; phy < 2; ++phy) {
      const int y = ty0 + 4 * wv + 2 * g + phy;
      const int x0 = tx0 + 2 * nl;                     // phx=0 pixel; phx=1 is x0+1
      float s0 = 0.f, s1 = 0.f;
      #pragma unroll
      for (int r = 0; r < 4; ++r) {
        s0 += w5v[r] * fmaxf(acc[g * 4 + 2 * phy + 0][r] + bv[r], 0.f);
        s1 += w5v[r] * fmaxf(acc[g * 4 + 2 * phy + 1][r] + bv[r], 0.f);
      }
      s0 += __shfl_xor(s0, 16); s0 += __shfl_xor(s0, 32);
      s1 += __shfl_xor(s1, 16); s1 += __shfl_xor(s1, 32);
      if (q == 0) {
        // gray bilinear: input rows 4y+1,4y+2; cols 4x+1,4x+2 for x = x0, x0+1.
        // float4 pair at 4*x0 covers both pixels; 16 lanes x 32B = contiguous.
        const size_t cb = (size_t)(4 * y + 1) * IN_W + 4 * x0;
        float g0 = 0.f, g1 = 0.f;
        #pragma unroll
        for (int ch = 0; ch < 3; ++ch) {
          const float coef = (ch == 0) ? 0.299f : ((ch == 1) ? 0.587f : 0.114f);
          const float* qp = inb + (size_t)ch * (IN_H * IN_W);
          float4 a0 = *(const float4*)(qp + cb);
          float4 a1 = *(const float4*)(qp + cb + 4);
          float4 d0 = *(const float4*)(qp + cb + IN_W);
          float4 d1 = *(const float4*)(qp + cb + IN_W + 4);
          g0 += coef * (a0.y + a0.z + d0.y + d0.z);
          g1 += coef * (a1.y + a1.z + d1.y + d1.z);
        }
        float o0 = fmaxf(s0 + b5v + fmaxf(g0 * 0.25f, 0.f), 0.f);
        float o1 = fmaxf(s1 + b5v + fmaxf(g1 * 0.25f, 0.f), 0.f);
        *(float2*)(out + ((size_t)b * P2H + y) * P2W + x0) = make_float2(o0, o1);
      }
    }
}

extern "C" void kernel_launch(void* const* d_in, const int* in_sizes, int n_in,
                              void* d_out, int out_size, void* d_ws, size_t ws_size,
                              hipStream_t stream) {
  const float* input = (const float*)d_in[0];
  const float* w1 = (const float*)d_in[1];  const float* b1 = (const float*)d_in[2];
  const float* w2 = (const float*)d_in[3];  const float* b2 = (const float*)d_in[4];
  const float* w3 = (const float*)d_in[5];  const float* b3 = (const float*)d_in[6];
  const float* w4 = (const float*)d_in[7];  const float* b4 = (const float*)d_in[8];
  const float* w5 = (const float*)d_in[9];  const float* b5 = (const float*)d_in[10];
  float* out = (float*)d_out;
  char* ws = (char*)d_ws;

  half_t* P2h = (half_t*)(ws + OFF_P2);
  half_t* P1h = (half_t*)(ws + OFF_P1);
  half_t* X3h = (half_t*)(ws + OFF_X3);
  half_t* wp2 = (half_t*)(ws + OFF_W2);
  half_t* wp3 = (half_t*)(ws + OFF_W3);
  half_t* wp4 = (half_t*)(ws + OFF_W4);
  half_t* wp1 = (half_t*)(ws + OFF_W1);

  pack_weights<<<432, 256, 0, stream>>>(w2, w3, w4, w1, wp2, wp3, wp4, wp1);
  conv1_mfma<<<dim3(32, 24, 8), 256, 0, stream>>>(input, wp1, b1, P1h);
  conv2_mfma<<<dim3(16, 24, 8), 256, 0, stream>>>(P1h, wp2, b2, P2h);
  conv3_mfma<<<dim3(8, 24, 8), 256, 0, stream>>>(P2h, wp3, b3, X3h);
  conv4_mfma<<<dim3(8, 12, 8), 256, 0, stream>>>(X3h, wp4, b4, w5, b5, input, out);
}